// Round 5
// baseline (346.678 us; speedup 1.0000x reference)
//
#include <hip/hip_runtime.h>
#include <hip/hip_bf16.h>

#define HIDDEN 512
#define IMGF   2048
#define RNDS   10

typedef float  f32x4  __attribute__((ext_vector_type(4)));
typedef __bf16 bf16x8 __attribute__((ext_vector_type(8)));
typedef unsigned short u16x8 __attribute__((ext_vector_type(8)));

__device__ __forceinline__ unsigned short f2bf(float x) {
    union { float f; unsigned u; } v; v.f = x;
    unsigned r = v.u + 0x7FFFu + ((v.u >> 16) & 1u);   // RNE
    return (unsigned short)(r >> 16);
}
__device__ __forceinline__ float bf2f(unsigned short h) {
    union { unsigned u; float f; } v; v.u = ((unsigned)h) << 16;
    return v.f;
}

__device__ __forceinline__ void cp16_async(const void* g, void* l) {
    __builtin_amdgcn_global_load_lds(
        (const __attribute__((address_space(1))) unsigned int*)g,
        (__attribute__((address_space(3))) unsigned int*)l,
        16, 0, 0);
}

// Pack 8 consecutive fp32 (two float4) -> bf16x8 fragment (v_cvt_pk_bf16_f32)
__device__ __forceinline__ bf16x8 pack8(float4 p0, float4 p1) {
    union { bf16x8 v; __hip_bfloat162 h[4]; } u;
    u.h[0] = __float22bfloat162_rn(make_float2(p0.x, p0.y));
    u.h[1] = __float22bfloat162_rn(make_float2(p0.z, p0.w));
    u.h[2] = __float22bfloat162_rn(make_float2(p1.x, p1.y));
    u.h[3] = __float22bfloat162_rn(make_float2(p1.z, p1.w));
    return u.v;
}

// ---------------------------------------------------------------------------
// fp32 -> bf16 pre-convert, WEIGHTS ONLY (W_fuse + W_hist, 6.3 MB read)
// ---------------------------------------------------------------------------
__global__ __launch_bounds__(256)
void cvt_bf16(const float* __restrict__ p0, long n0,
              const float* __restrict__ p1, long n1,
              unsigned short* __restrict__ q0, unsigned short* __restrict__ q1)
{
    long i = ((long)blockIdx.x * 256 + threadIdx.x) * 4;
    const float* s; unsigned short* d; long j;
    if (i < n0) { s = p0; d = q0; j = i; }
    else        { s = p1; d = q1; j = i - n0; }
    float4 v = *(const float4*)(s + j);
    ushort4 o;
    o.x = f2bf(v.x); o.y = f2bf(v.y); o.z = f2bf(v.z); o.w = f2bf(v.w);
    *(ushort4*)(d + j) = o;
}

// ---------------------------------------------------------------------------
// GEMM1: fusedb[m][n] = tanh( sum_k cat(img,ques)[m][k] * W[n][k] + bias[n] )
// A: fp32 direct global->VGPR, prefetched ONE FULL K-TILE ahead (in-flight
//    capacity = VGPRs, not the shallow LDS-DMA queue that capped staging at
//    ~340 GB/s in rounds 2-4). Packed to bf16 in-register at use time.
// B: bf16 (L2-resident slice per bn) via global_load_lds, double-buffered,
//    XOR-swizzled. Grid: bn = id&7 (per-XCD B slice 320 KB stays L2-hot),
//    bm = id>>3 (8 bn-blocks of one bm co-scheduled -> A fetched from HBM once).
// 256 threads = 4 waves, wave tile 32x32, block tile 64x64, 640 blocks.
// ---------------------------------------------------------------------------
__global__ __launch_bounds__(256, 2)
void gemm1(const float* __restrict__ img,          // [.,2048] fp32
           const float* __restrict__ ques,         // [.,512]  fp32
           const unsigned short* __restrict__ W,   // bf16 [512,2560]
           const float* __restrict__ bias,
           unsigned short* __restrict__ outb)      // fused bf16 [.,512]
{
    __shared__ unsigned short lB[2][64 * 64];
    const int id = blockIdx.x;
    const int bm = (id >> 3) * 64;
    const int bn = (id & 7) * 64;
    const int t = threadIdx.x, lane = t & 63, wv = t >> 6;
    const int wm = (wv & 1) * 32, wn = (wv >> 1) * 32;
    const int lr = lane & 15, lq = lane >> 4;
    const int K = IMGF + HIDDEN;                   // 2560

    const unsigned short* Wb0 = W + (size_t)bn * K;
    auto stageB = [&](int kt, int buf) {
        const unsigned short* src = Wb0 + (kt << 6);
        #pragma unroll
        for (int h = 0; h < 2; ++h) {              // 512 chunks / 256 thr
            int ci = h * 256 + t;
            int r = ci >> 3, s = (ci & 7) ^ (r & 7);
            cp16_async(src + (size_t)r * K + s * 8, &lB[buf][ci * 8]);
        }
    };

    const int row0 = bm + wm + lr, row1 = row0 + 16;
    float4 rF[2][2][2];                            // [kh][mi][half]
    auto prefetchA = [&](int kt) {
        int k0 = kt << 6;
        const float* Ab; int lda, ko;              // wave-uniform concat select
        if (k0 < IMGF) { Ab = img;  lda = IMGF;   ko = k0; }
        else           { Ab = ques; lda = HIDDEN; ko = k0 - IMGF; }
        #pragma unroll
        for (int kh = 0; kh < 2; ++kh) {
            const float* p0 = Ab + (size_t)row0 * lda + ko + kh * 32 + lq * 8;
            const float* p1 = Ab + (size_t)row1 * lda + ko + kh * 32 + lq * 8;
            rF[kh][0][0] = *(const float4*)p0;  rF[kh][0][1] = *(const float4*)(p0 + 4);
            rF[kh][1][0] = *(const float4*)p1;  rF[kh][1][1] = *(const float4*)(p1 + 4);
        }
    };

    f32x4 acc[2][2] = {};
    const int NT = K >> 6;                         // 40

    prefetchA(0);
    stageB(0, 0);
    for (int kt = 0; kt < NT; ++kt) {
        // consume rF (tile kt) into bf16 frags BEFORE reloading rF
        bf16x8 af[2][2];
        #pragma unroll
        for (int kh = 0; kh < 2; ++kh)
            #pragma unroll
            for (int mi = 0; mi < 2; ++mi)
                af[kh][mi] = pack8(rF[kh][mi][0], rF[kh][mi][1]);
        __syncthreads();                           // B[kt&1] ready
        if (kt + 1 < NT) {
            stageB(kt + 1, (kt + 1) & 1);          // async -> other buffer
            prefetchA(kt + 1);                     // global->VGPR, lands by next pack
        }
        const unsigned short* b = &lB[kt & 1][0];
        #pragma unroll
        for (int kh = 0; kh < 2; ++kh) {
            const int c = kh * 4 + lq;
            #pragma unroll
            for (int ni = 0; ni < 2; ++ni) {
                const int rb = wn + ni * 16 + lr;
                bf16x8 bfr = __builtin_bit_cast(bf16x8,
                    *(const u16x8*)&b[rb * 64 + ((c ^ (rb & 7)) * 8)]);
                #pragma unroll
                for (int mi = 0; mi < 2; ++mi)
                    acc[mi][ni] = __builtin_amdgcn_mfma_f32_16x16x32_bf16(
                        af[kh][mi], bfr, acc[mi][ni], 0, 0, 0);
            }
        }
    }

    // epilogue: D[m = lq*4 + j][n = lr]  (verified m89/m91 layout)
    #pragma unroll
    for (int ni = 0; ni < 2; ++ni) {
        const int col = bn + wn + ni * 16 + lr;
        const float bc = bias[col];
        #pragma unroll
        for (int mi = 0; mi < 2; ++mi) {
            const int rbase = bm + wm + mi * 16 + lq * 4;
            #pragma unroll
            for (int j = 0; j < 4; ++j)
                outb[(size_t)(rbase + j) * HIDDEN + col] =
                    f2bf(tanhf(acc[mi][ni][j] + bc));
        }
    }
}

// ---------------------------------------------------------------------------
// GEMM2: out[m][n] = fusedb[m][n] + tanh( sum_k hemb[m][k]*W_hist[n][k]+b[n] )
// Same structure; A (hemb bf16) direct global->VGPR fragments, K=512.
// ---------------------------------------------------------------------------
__global__ __launch_bounds__(256, 2)
void gemm2(const unsigned short* __restrict__ A,   // hemb bf16 [.,512]
           const unsigned short* __restrict__ W,   // W_hist bf16 [512,512]
           const float* __restrict__ bias,
           const unsigned short* __restrict__ residb,
           float* __restrict__ outf)
{
    __shared__ unsigned short lB[2][64 * 64];
    const int id = blockIdx.x;
    const int bm = (id >> 3) * 64;
    const int bn = (id & 7) * 64;
    const int t = threadIdx.x, lane = t & 63, wv = t >> 6;
    const int wm = (wv & 1) * 32, wn = (wv >> 1) * 32;
    const int lr = lane & 15, lq = lane >> 4;
    const int K = HIDDEN;                          // 512

    const unsigned short* Wb0 = W + (size_t)bn * K;
    auto stageB = [&](int kt, int buf) {
        const unsigned short* src = Wb0 + (kt << 6);
        #pragma unroll
        for (int h = 0; h < 2; ++h) {
            int ci = h * 256 + t;
            int r = ci >> 3, s = (ci & 7) ^ (r & 7);
            cp16_async(src + (size_t)r * K + s * 8, &lB[buf][ci * 8]);
        }
    };

    const int row0 = bm + wm + lr, row1 = row0 + 16;
    u16x8 rA[2][2];                                // [kh][mi]
    auto prefetchA = [&](int kt) {
        int k0 = kt << 6;
        #pragma unroll
        for (int kh = 0; kh < 2; ++kh) {
            rA[kh][0] = *(const u16x8*)(A + (size_t)row0 * K + k0 + kh * 32 + lq * 8);
            rA[kh][1] = *(const u16x8*)(A + (size_t)row1 * K + k0 + kh * 32 + lq * 8);
        }
    };

    f32x4 acc[2][2] = {};
    const int NT = K >> 6;                         // 8

    prefetchA(0);
    stageB(0, 0);
    for (int kt = 0; kt < NT; ++kt) {
        bf16x8 af[2][2];
        #pragma unroll
        for (int kh = 0; kh < 2; ++kh)
            #pragma unroll
            for (int mi = 0; mi < 2; ++mi)
                af[kh][mi] = __builtin_bit_cast(bf16x8, rA[kh][mi]);
        __syncthreads();
        if (kt + 1 < NT) {
            stageB(kt + 1, (kt + 1) & 1);
            prefetchA(kt + 1);
        }
        const unsigned short* b = &lB[kt & 1][0];
        #pragma unroll
        for (int kh = 0; kh < 2; ++kh) {
            const int c = kh * 4 + lq;
            #pragma unroll
            for (int ni = 0; ni < 2; ++ni) {
                const int rb = wn + ni * 16 + lr;
                bf16x8 bfr = __builtin_bit_cast(bf16x8,
                    *(const u16x8*)&b[rb * 64 + ((c ^ (rb & 7)) * 8)]);
                #pragma unroll
                for (int mi = 0; mi < 2; ++mi)
                    acc[mi][ni] = __builtin_amdgcn_mfma_f32_16x16x32_bf16(
                        af[kh][mi], bfr, acc[mi][ni], 0, 0, 0);
            }
        }
    }

    #pragma unroll
    for (int ni = 0; ni < 2; ++ni) {
        const int col = bn + wn + ni * 16 + lr;
        const float bc = bias[col];
        #pragma unroll
        for (int mi = 0; mi < 2; ++mi) {
            const int rbase = bm + wm + mi * 16 + lq * 4;
            #pragma unroll
            for (int j = 0; j < 4; ++j) {
                const size_t idx = (size_t)(rbase + j) * HIDDEN + col;
                outf[idx] = tanhf(acc[mi][ni][j] + bc) + bf2f(residb[idx]);
            }
        }
    }
}

// ---------------------------------------------------------------------------
// Attention: one wave per BR-row, lane holds 8 dims x 10 rounds in registers.
// No LDS, no barriers. fused is bf16; writes hist_embed as bf16 (GEMM2's A).
// ---------------------------------------------------------------------------
__global__ __launch_bounds__(256)
void attn_embed(const float* __restrict__ hist,
                const unsigned short* __restrict__ fusedb,
                const float* __restrict__ w_att,
                const float* __restrict__ b_att,
                unsigned short* __restrict__ hembed)
{
    const int lane = threadIdx.x & 63;
    const int wave = threadIdx.x >> 6;
    const int b = blockIdx.x * 4 + wave;
    const int d = lane * 8;

    float g[8];
    {
        u16x8 f = *(const u16x8*)(fusedb + (size_t)b * HIDDEN + d);
        const float4 w0 = *(const float4*)(w_att + d);
        const float4 w1 = *(const float4*)(w_att + d + 4);
        g[0]=bf2f(f[0])*w0.x; g[1]=bf2f(f[1])*w0.y; g[2]=bf2f(f[2])*w0.z; g[3]=bf2f(f[3])*w0.w;
        g[4]=bf2f(f[4])*w1.x; g[5]=bf2f(f[5])*w1.y; g[6]=bf2f(f[6])*w1.z; g[7]=bf2f(f[7])*w1.w;
    }
    const float* hb = hist + (size_t)b * RNDS * HIDDEN + d;

    float h[RNDS][8], p[RNDS];
    #pragma unroll
    for (int r = 0; r < RNDS; ++r) {
        const float4 a0 = *(const float4*)(hb + r * HIDDEN);
        const float4 a1 = *(const float4*)(hb + r * HIDDEN + 4);
        h[r][0]=a0.x; h[r][1]=a0.y; h[r][2]=a0.z; h[r][3]=a0.w;
        h[r][4]=a1.x; h[r][5]=a1.y; h[r][6]=a1.z; h[r][7]=a1.w;
        float s = 0.f;
        #pragma unroll
        for (int i = 0; i < 8; ++i) s += h[r][i] * g[i];
        p[r] = s;
    }
    #pragma unroll
    for (int r = 0; r < RNDS; ++r)
        #pragma unroll
        for (int m = 1; m < 64; m <<= 1)
            p[r] += __shfl_xor(p[r], m, 64);

    const float ba = b_att[0];
    float mx = -1e30f;
    #pragma unroll
    for (int r = 0; r < RNDS; ++r) mx = fmaxf(mx, p[r] + ba);
    float sum = 0.f, a[RNDS];
    #pragma unroll
    for (int r = 0; r < RNDS; ++r) { a[r] = __expf(p[r] + ba - mx); sum += a[r]; }
    const float inv = 1.0f / sum;

    float e[8] = {};
    #pragma unroll
    for (int r = 0; r < RNDS; ++r)
        #pragma unroll
        for (int i = 0; i < 8; ++i) e[i] += a[r] * h[r][i];

    ushort4 o0, o1;
    o0.x=f2bf(e[0]*inv); o0.y=f2bf(e[1]*inv); o0.z=f2bf(e[2]*inv); o0.w=f2bf(e[3]*inv);
    o1.x=f2bf(e[4]*inv); o1.y=f2bf(e[5]*inv); o1.z=f2bf(e[6]*inv); o1.w=f2bf(e[7]*inv);
    unsigned short* q = hembed + (size_t)b * HIDDEN + d;
    *(ushort4*)q = o0;
    *(ushort4*)(q + 4) = o1;
}

extern "C" void kernel_launch(void* const* d_in, const int* in_sizes, int n_in,
                              void* d_out, int out_size, void* d_ws, size_t ws_size,
                              hipStream_t stream)
{
    const float* img    = (const float*)d_in[0];
    const float* ques   = (const float*)d_in[1];
    const float* hist   = (const float*)d_in[2];
    const float* W_fuse = (const float*)d_in[3];
    const float* b_fuse = (const float*)d_in[4];
    const float* w_att  = (const float*)d_in[5];
    const float* b_att  = (const float*)d_in[6];
    const float* W_hist = (const float*)d_in[7];
    const float* b_hist = (const float*)d_in[8];

    const long n_Wf = in_sizes[3];               // 512*2560
    const long n_Wh = in_sizes[7];               // 512*512
    const int  BR   = in_sizes[1] / HIDDEN;      // 5120

    unsigned short* Wfb    = (unsigned short*)d_ws;
    unsigned short* Whb    = Wfb    + n_Wf;
    unsigned short* fusedb = Whb    + n_Wh;      // BR*512 bf16
    unsigned short* hembb  = fusedb + (size_t)BR * HIDDEN;

    // 1) weights fp32 -> bf16 (6.3 MB)
    const long total4 = (n_Wf + n_Wh) / 4;
    cvt_bf16<<<dim3((unsigned)((total4 + 255) / 256)), dim3(256), 0, stream>>>(
        W_fuse, n_Wf, W_hist, n_Wh, Wfb, Whb);

    const int nblk = (BR / 64) * (HIDDEN / 64);  // 640

    // 2) fusedb = tanh(cat(img,ques) @ W_fuse^T + b_fuse)   (bf16)
    gemm1<<<dim3(nblk), dim3(256), 0, stream>>>(
        img, ques, Wfb, b_fuse, fusedb);

    // 3) attention + weighted history sum -> hembb (bf16)
    attn_embed<<<dim3(BR / 4), dim3(256), 0, stream>>>(
        hist, fusedb, w_att, b_att, hembb);

    // 4) out = fusedb + tanh(hembb @ W_hist^T + b_hist)
    gemm2<<<dim3(nblk), dim3(256), 0, stream>>>(
        hembb, Whb, b_hist, fusedb, (float*)d_out);
}

// Round 6
// 267.531 us; speedup vs baseline: 1.2958x; 1.2958x over previous
//
#include <hip/hip_runtime.h>
#include <hip/hip_bf16.h>

#define HIDDEN 512
#define IMGF   2048
#define RNDS   10

typedef float  f32x4  __attribute__((ext_vector_type(4)));
typedef __bf16 bf16x8 __attribute__((ext_vector_type(8)));
typedef unsigned short u16x8 __attribute__((ext_vector_type(8)));

__device__ __forceinline__ unsigned short f2bf(float x) {
    union { float f; unsigned u; } v; v.f = x;
    unsigned r = v.u + 0x7FFFu + ((v.u >> 16) & 1u);   // RNE
    return (unsigned short)(r >> 16);
}
__device__ __forceinline__ float bf2f(unsigned short h) {
    union { unsigned u; float f; } v; v.u = ((unsigned)h) << 16;
    return v.f;
}

__device__ __forceinline__ void cp16_async(const void* g, void* l) {
    __builtin_amdgcn_global_load_lds(
        (const __attribute__((address_space(1))) unsigned int*)g,
        (__attribute__((address_space(3))) unsigned int*)l,
        16, 0, 0);
}

// Pack 8 consecutive fp32 (two float4) -> bf16x8 fragment (v_cvt_pk_bf16_f32)
__device__ __forceinline__ bf16x8 pack8(float4 p0, float4 p1) {
    union { bf16x8 v; __hip_bfloat162 h[4]; } u;
    u.h[0] = __float22bfloat162_rn(make_float2(p0.x, p0.y));
    u.h[1] = __float22bfloat162_rn(make_float2(p0.z, p0.w));
    u.h[2] = __float22bfloat162_rn(make_float2(p1.x, p1.y));
    u.h[3] = __float22bfloat162_rn(make_float2(p1.z, p1.w));
    return u.v;
}

// ---------------------------------------------------------------------------
// fp32 -> bf16 pre-convert, WEIGHTS ONLY (W_fuse + W_hist, 6.3 MB read)
// ---------------------------------------------------------------------------
__global__ __launch_bounds__(256)
void cvt_bf16(const float* __restrict__ p0, long n0,
              const float* __restrict__ p1, long n1,
              unsigned short* __restrict__ q0, unsigned short* __restrict__ q1)
{
    long i = ((long)blockIdx.x * 256 + threadIdx.x) * 4;
    const float* s; unsigned short* d; long j;
    if (i < n0) { s = p0; d = q0; j = i; }
    else        { s = p1; d = q1; j = i - n0; }
    float4 v = *(const float4*)(s + j);
    ushort4 o;
    o.x = f2bf(v.x); o.y = f2bf(v.y); o.z = f2bf(v.z); o.w = f2bf(v.w);
    *(ushort4*)(d + j) = o;
}

// ---------------------------------------------------------------------------
// GEMM1: fusedb[m][n] = tanh( sum_k cat(img,ques)[m][k] * W[n][k] + bias[n] )
// PROVEN r2/r3 structure: ALL staging through global_load_lds, double-buffered,
// XOR-swizzled; A staged as RAW FP32 (no pre-convert pass), converted to bf16
// in-register (cvt_pk) after ds_read_b128.
//   A swizzle: 16 chunks/row of 16B; phys = c ^ (row & 15)  -> 2-way max (free)
//   B swizzle:  8 chunks/row of 16B; phys = c ^ (row & 7)   -> proven r2/r3
// Grid (80,8): linear id = bx + 80*by; 80 % 8 == 0 so the 8 bn-blocks of one
// bm share id%8 -> SAME XCD -> A tile HBM-fetched once, 8x L2 reuse.
// 256 thr = 4 waves, wave tile 32x32, block tile 64x64, LDS 48 KB (3 blk/CU).
// ---------------------------------------------------------------------------
__global__ __launch_bounds__(256, 3)
void gemm1(const float* __restrict__ img,          // [.,2048] fp32
           const float* __restrict__ ques,         // [.,512]  fp32
           const unsigned short* __restrict__ W,   // bf16 [512,2560]
           const float* __restrict__ bias,
           unsigned short* __restrict__ outb)      // fused bf16 [.,512]
{
    __shared__ float          lA[2][64 * 64];      // fp32 A tile (swizzled)
    __shared__ unsigned short lB[2][64 * 64];      // bf16 B tile (swizzled)
    const int bm = blockIdx.x * 64;
    const int bn = blockIdx.y * 64;
    const int t = threadIdx.x, lane = t & 63, wv = t >> 6;
    const int wm = (wv & 1) * 32, wn = (wv >> 1) * 32;
    const int lr = lane & 15, lq = lane >> 4;
    const int K = IMGF + HIDDEN;                   // 2560

    const unsigned short* Wb0 = W + (size_t)bn * K;
    auto stageB = [&](int kt, int buf) {
        const unsigned short* src = Wb0 + (kt << 6);
        #pragma unroll
        for (int h = 0; h < 2; ++h) {              // 512 chunks of 16B
            int ci = h * 256 + t;
            int r = ci >> 3, c = (ci & 7) ^ (r & 7);
            cp16_async(src + (size_t)r * K + c * 8, &lB[buf][ci * 8]);
        }
    };
    auto stageA = [&](int kt, int buf) {
        int k0 = kt << 6;
        const float* Ab; int lda, ko;              // uniform concat select
        if (k0 < IMGF) { Ab = img  + (size_t)bm * IMGF;   lda = IMGF;   ko = k0; }
        else           { Ab = ques + (size_t)bm * HIDDEN; lda = HIDDEN; ko = k0 - IMGF; }
        #pragma unroll
        for (int h = 0; h < 4; ++h) {              // 1024 chunks of 16B (4 fp32)
            int ci = h * 256 + t;
            int r = ci >> 4, c = (ci & 15) ^ (r & 15);
            cp16_async(Ab + (size_t)r * lda + ko + c * 4, &lA[buf][ci * 4]);
        }
    };

    f32x4 acc[2][2] = {};
    const int NT = K >> 6;                         // 40

    stageA(0, 0);
    stageB(0, 0);
    for (int kt = 0; kt < NT; ++kt) {
        __syncthreads();                           // drain DMA -> buf kt ready
        if (kt + 1 < NT) { stageA(kt + 1, (kt + 1) & 1); stageB(kt + 1, (kt + 1) & 1); }
        const float*          a = &lA[kt & 1][0];
        const unsigned short* b = &lB[kt & 1][0];
        #pragma unroll
        for (int kh = 0; kh < 2; ++kh) {
            const int c0 = kh * 8 + lq * 2;        // logical 16B chunk (fp32 A)
            bf16x8 af[2];
            #pragma unroll
            for (int mi = 0; mi < 2; ++mi) {
                const int ra = wm + mi * 16 + lr;  // ra & 15 == lr
                float4 p0 = *(const float4*)&a[ra * 64 + ((c0     ^ lr) * 4)];
                float4 p1 = *(const float4*)&a[ra * 64 + (((c0+1) ^ lr) * 4)];
                af[mi] = pack8(p0, p1);
            }
            const int cb = kh * 4 + lq;            // logical 16B chunk (bf16 B)
            #pragma unroll
            for (int ni = 0; ni < 2; ++ni) {
                const int rb = wn + ni * 16 + lr;  // rb & 7 == lr & 7
                bf16x8 bfr = __builtin_bit_cast(bf16x8,
                    *(const u16x8*)&b[rb * 64 + ((cb ^ (lr & 7)) * 8)]);
                #pragma unroll
                for (int mi = 0; mi < 2; ++mi)
                    acc[mi][ni] = __builtin_amdgcn_mfma_f32_16x16x32_bf16(
                        af[mi], bfr, acc[mi][ni], 0, 0, 0);
            }
        }
    }

    // epilogue: D[m = lq*4 + j][n = lr]  (verified m89/m91 layout)
    #pragma unroll
    for (int ni = 0; ni < 2; ++ni) {
        const int col = bn + wn + ni * 16 + lr;
        const float bc = bias[col];
        #pragma unroll
        for (int mi = 0; mi < 2; ++mi) {
            const int rbase = bm + wm + mi * 16 + lq * 4;
            #pragma unroll
            for (int j = 0; j < 4; ++j)
                outb[(size_t)(rbase + j) * HIDDEN + col] =
                    f2bf(tanhf(acc[mi][ni][j] + bc));
        }
    }
}

// ---------------------------------------------------------------------------
// GEMM2: out[m][n] = fusedb[m][n] + tanh( sum_k hemb[m][k]*W_hist[n][k]+b[n] )
// Proven r2-style: both A (bf16) and B via global_load_lds, dbuf, swizzled.
// ---------------------------------------------------------------------------
__global__ __launch_bounds__(256, 4)
void gemm2(const unsigned short* __restrict__ A,   // hemb bf16 [.,512]
           const unsigned short* __restrict__ W,   // W_hist bf16 [512,512]
           const float* __restrict__ bias,
           const unsigned short* __restrict__ residb,
           float* __restrict__ outf)
{
    __shared__ unsigned short lA[2][64 * 64];
    __shared__ unsigned short lB[2][64 * 64];
    const int bm = blockIdx.x * 64;
    const int bn = blockIdx.y * 64;
    const int t = threadIdx.x, lane = t & 63, wv = t >> 6;
    const int wm = (wv & 1) * 32, wn = (wv >> 1) * 32;
    const int lr = lane & 15, lq = lane >> 4;
    const int K = HIDDEN;                          // 512

    const unsigned short* Ab0 = A + (size_t)bm * K;
    const unsigned short* Wb0 = W + (size_t)bn * K;
    auto stage = [&](int kt, int buf) {
        const unsigned short* sa = Ab0 + (kt << 6);
        const unsigned short* sb = Wb0 + (kt << 6);
        #pragma unroll
        for (int h = 0; h < 2; ++h) {
            int ci = h * 256 + t;
            int r = ci >> 3, c = (ci & 7) ^ (r & 7);
            cp16_async(sa + (size_t)r * K + c * 8, &lA[buf][ci * 8]);
            cp16_async(sb + (size_t)r * K + c * 8, &lB[buf][ci * 8]);
        }
    };

    f32x4 acc[2][2] = {};
    const int NT = K >> 6;                         // 8

    stage(0, 0);
    for (int kt = 0; kt < NT; ++kt) {
        __syncthreads();
        if (kt + 1 < NT) stage(kt + 1, (kt + 1) & 1);
        const unsigned short* a = &lA[kt & 1][0];
        const unsigned short* b = &lB[kt & 1][0];
        #pragma unroll
        for (int kh = 0; kh < 2; ++kh) {
            const int c = kh * 4 + lq;
            bf16x8 af[2];
            #pragma unroll
            for (int mi = 0; mi < 2; ++mi) {
                const int ra = wm + mi * 16 + lr;
                af[mi] = __builtin_bit_cast(bf16x8,
                    *(const u16x8*)&a[ra * 64 + ((c ^ (lr & 7)) * 8)]);
            }
            #pragma unroll
            for (int ni = 0; ni < 2; ++ni) {
                const int rb = wn + ni * 16 + lr;
                bf16x8 bfr = __builtin_bit_cast(bf16x8,
                    *(const u16x8*)&b[rb * 64 + ((c ^ (lr & 7)) * 8)]);
                #pragma unroll
                for (int mi = 0; mi < 2; ++mi)
                    acc[mi][ni] = __builtin_amdgcn_mfma_f32_16x16x32_bf16(
                        af[mi], bfr, acc[mi][ni], 0, 0, 0);
            }
        }
    }

    #pragma unroll
    for (int ni = 0; ni < 2; ++ni) {
        const int col = bn + wn + ni * 16 + lr;
        const float bc = bias[col];
        #pragma unroll
        for (int mi = 0; mi < 2; ++mi) {
            const int rbase = bm + wm + mi * 16 + lq * 4;
            #pragma unroll
            for (int j = 0; j < 4; ++j) {
                const size_t idx = (size_t)(rbase + j) * HIDDEN + col;
                outf[idx] = tanhf(acc[mi][ni][j] + bc) + bf2f(residb[idx]);
            }
        }
    }
}

// ---------------------------------------------------------------------------
// Attention: 2 rows/block, HALF-row (256 dims) per wave -> 2x wave count
// (10240 waves, ~40/CU target) for latency hiding on the 105 MB hist stream.
// Cross-wave score reduce via tiny LDS; softmax redundant per wave.
// ---------------------------------------------------------------------------
__global__ __launch_bounds__(256)
void attn_embed(const float* __restrict__ hist,
                const unsigned short* __restrict__ fusedb,
                const float* __restrict__ w_att,
                const float* __restrict__ b_att,
                unsigned short* __restrict__ hembed)
{
    __shared__ float red[2][RNDS][2];
    const int t = threadIdx.x, lane = t & 63, wave = t >> 6;
    const int rowL = wave >> 1, half = wave & 1;
    const int b = blockIdx.x * 2 + rowL;
    const int d = half * 256 + lane * 4;

    float g[4];
    {
        ushort4 f = *(const ushort4*)(fusedb + (size_t)b * HIDDEN + d);
        float4  w = *(const float4*)(w_att + d);
        g[0] = bf2f(f.x) * w.x; g[1] = bf2f(f.y) * w.y;
        g[2] = bf2f(f.z) * w.z; g[3] = bf2f(f.w) * w.w;
    }
    const float* hb = hist + (size_t)b * RNDS * HIDDEN + d;

    float h[RNDS][4], p[RNDS];
    #pragma unroll
    for (int r = 0; r < RNDS; ++r) {
        float4 a = *(const float4*)(hb + r * HIDDEN);
        h[r][0] = a.x; h[r][1] = a.y; h[r][2] = a.z; h[r][3] = a.w;
        p[r] = a.x * g[0] + a.y * g[1] + a.z * g[2] + a.w * g[3];
    }
    #pragma unroll
    for (int r = 0; r < RNDS; ++r)
        #pragma unroll
        for (int m = 1; m < 64; m <<= 1)
            p[r] += __shfl_xor(p[r], m, 64);
    if (lane == 0)
        #pragma unroll
        for (int r = 0; r < RNDS; ++r) red[rowL][r][half] = p[r];
    __syncthreads();

    const float ba = b_att[0];
    float sc[RNDS], mx = -1e30f;
    #pragma unroll
    for (int r = 0; r < RNDS; ++r) {
        sc[r] = red[rowL][r][0] + red[rowL][r][1] + ba;
        mx = fmaxf(mx, sc[r]);
    }
    float sum = 0.f, a[RNDS];
    #pragma unroll
    for (int r = 0; r < RNDS; ++r) { a[r] = __expf(sc[r] - mx); sum += a[r]; }
    const float inv = 1.0f / sum;

    float e[4] = {};
    #pragma unroll
    for (int r = 0; r < RNDS; ++r)
        #pragma unroll
        for (int i = 0; i < 4; ++i) e[i] += a[r] * h[r][i];

    ushort4 o;
    o.x = f2bf(e[0] * inv); o.y = f2bf(e[1] * inv);
    o.z = f2bf(e[2] * inv); o.w = f2bf(e[3] * inv);
    *(ushort4*)(hembed + (size_t)b * HIDDEN + d) = o;
}

extern "C" void kernel_launch(void* const* d_in, const int* in_sizes, int n_in,
                              void* d_out, int out_size, void* d_ws, size_t ws_size,
                              hipStream_t stream)
{
    const float* img    = (const float*)d_in[0];
    const float* ques   = (const float*)d_in[1];
    const float* hist   = (const float*)d_in[2];
    const float* W_fuse = (const float*)d_in[3];
    const float* b_fuse = (const float*)d_in[4];
    const float* w_att  = (const float*)d_in[5];
    const float* b_att  = (const float*)d_in[6];
    const float* W_hist = (const float*)d_in[7];
    const float* b_hist = (const float*)d_in[8];

    const long n_Wf = in_sizes[3];               // 512*2560
    const long n_Wh = in_sizes[7];               // 512*512
    const int  BR   = in_sizes[1] / HIDDEN;      // 5120

    unsigned short* Wfb    = (unsigned short*)d_ws;
    unsigned short* Whb    = Wfb    + n_Wf;
    unsigned short* fusedb = Whb    + n_Wh;      // BR*512 bf16
    unsigned short* hembb  = fusedb + (size_t)BR * HIDDEN;

    // 1) weights fp32 -> bf16 (6.3 MB)
    const long total4 = (n_Wf + n_Wh) / 4;
    cvt_bf16<<<dim3((unsigned)((total4 + 255) / 256)), dim3(256), 0, stream>>>(
        W_fuse, n_Wf, W_hist, n_Wh, Wfb, Whb);

    dim3 g(BR / 64, HIDDEN / 64);                // (80, 8)

    // 2) fusedb = tanh(cat(img,ques) @ W_fuse^T + b_fuse)   (bf16)
    gemm1<<<g, dim3(256), 0, stream>>>(img, ques, Wfb, b_fuse, fusedb);

    // 3) attention + weighted history sum -> hembb (bf16)
    attn_embed<<<dim3(BR / 2), dim3(256), 0, stream>>>(
        hist, fusedb, w_att, b_att, hembb);

    // 4) out = fusedb + tanh(hembb @ W_hist^T + b_hist)
    gemm2<<<g, dim3(256), 0, stream>>>(hembb, Whb, b_hist, fusedb, (float*)d_out);
}